// Round 12
// baseline (110.508 us; speedup 1.0000x reference)
//
#include <hip/hip_runtime.h>
#include <hip/hip_fp16.h>
#include <math.h>

#define PI_F      3.14159265358979323846f
#define TWO_PI_F  6.28318530717958647692f
#define PI4_F     0.78539816339744830962f   // pi/4 == ROT_SCALE == 2pi/8

typedef _Float16 f16x8 __attribute__((ext_vector_type(8)));
typedef float    f32x4 __attribute__((ext_vector_type(4)));

#define XH_OFF     ((size_t)1 << 20)                  // 1 MB
#define XH_BYTES   ((size_t)8 * 256 * 256 * 32 * 2)   // 33.55 MB

__device__ __forceinline__ float sgn(float t) {
    return (t > 0.f) ? 1.f : ((t < 0.f) ? -1.f : 0.f);
}

__device__ __forceinline__ float b2(float x) {
    float a = x - 0.5f;
    float b = x - 1.5f;
    float c = 1.f + 2.f * x;
    float d = 3.f + 2.f * x;
    return (-3.f * a * a * sgn(0.5f - x)
            + b * b * sgn(1.5f - x)
            - 0.75f * c * c * sgn(0.5f + x)
            + 0.25f * d * d * sgn(1.5f + x)) * 0.25f;
}

// ks_h[t][O][I] fp16.  t = dx*5+dy, O = r0*8+o, I = i*8+r
__global__ void build_ks_kernel(const float* __restrict__ w, __half* __restrict__ ksh) {
    int g = blockIdx.x * 256 + threadIdx.x;
    if (g >= 64 * 32 * 25) return;
    int O = g & 63;
    int rest = g >> 6;
    int t = rest % 25;
    int I = rest / 25;
    int r0 = O >> 3, o = O & 7;
    int i = I >> 3, r = I & 7;
    int x = t / 5, y = t % 5;

    float theta = -(float)r0 * PI4_F;
    float cth = cosf(theta), sth = sinf(theta);
    float fx = (float)(x - 2), fy = (float)(y - 2);
    float xc = fx * cth - fy * sth;
    float yc = fx * sth + fy * cth;

    float rotv[8];
    float rs = (float)r * PI4_F + theta;
    #pragma unroll
    for (int mr = 0; mr < 8; ++mr) {
        float v = (float)mr * PI4_F - rs + PI_F;
        float md = fmodf(v, TWO_PI_F);
        if (md < 0.f) md += TWO_PI_F;
        rotv[mr] = b2((md - PI_F) / PI4_F);
    }

    float sum = 0.f;
    for (int mx = 0; mx < 25; ++mx) {
        float cx = (float)(mx / 5 - 2);
        float cy = (float)(mx % 5 - 2);
        float bx = b2(cx - xc) * b2(cy - yc);
        if (bx != 0.f) {
            const float* wp = w + (size_t)(i * 200 + mx * 8) * 8 + o;
            #pragma unroll
            for (int mr = 0; mr < 8; ++mr)
                sum = fmaf(bx * rotv[mr], wp[mr * 8], sum);
        }
    }
    ksh[(size_t)(t * 64 + O) * 32 + I] = __float2half(sum);
}

// X (b,32ch,256,256) f32  ->  Xh (b,256,256,32ch) fp16.  One block per (b,h).
__global__ __launch_bounds__(256, 4) void hwc_kernel(const float* __restrict__ X,
                                                     __half* __restrict__ Xh) {
    int b = blockIdx.x >> 8;
    int h = blockIdx.x & 255;
    int ww = threadIdx.x;
    const float* Xb = X + ((size_t)b * 32) * 65536 + h * 256 + ww;

    union { __half hh[8]; uint4 u; } pk[4];
    #pragma unroll
    for (int c = 0; c < 32; ++c)
        pk[c >> 3].hh[c & 7] = __float2half(Xb[(size_t)c * 65536]);

    uint4* dst = (uint4*)(Xh + ((size_t)(b * 65536 + h * 256 + ww)) * 32);
    #pragma unroll
    for (int kk = 0; kk < 4; ++kk) dst[kk] = pk[kk].u;
}

// Implicit-GEMM conv: 32h x 32w px tile per 512-thread block (8 waves).
// LDS: xt[4 k-planes][1296 px (36x36 halo)] uint4 stride 1297 (83 KB)
//      + ks_s[13 tap slabs x 256 uint4] (53 KB) = 136 KB, 1 block/CU.
// ks is staged to LDS in two phases (taps 0..12, then 13..24) so B-reads
// are ds_read_b128 (no L1/L2 latency in the tap loop). A and B fragments
// are register-prefetched 1 tap deep: every ds_read is issued a full
// 32-MFMA burst (~620 cyc) before its lgkm wait.
__global__ __launch_bounds__(512, 2) void conv_hwc_kernel(const __half* __restrict__ Xh,
                                                          const __half* __restrict__ ksh,
                                                          float* __restrict__ out) {
    __shared__ uint4 xt[4 * 1297];    // 83,008 B
    __shared__ uint4 ks_s[13 * 256];  // 53,248 B

    int bid = blockIdx.x;
    int b   = bid >> 6;              // 8 batches, b-major
    int rem = bid & 63;              // 0..63
    int h0  = (rem >> 3) << 5;       // 8 h-strips of 32
    int w0  = (rem & 7) << 5;        // 8 w-strips of 32
    int tid = threadIdx.x;

    const char* Xb = (const char*)Xh + (size_t)b * ((size_t)65536 * 64);
    const uint4* ksq = (const uint4*)ksh;

    // ---- stage X tile (1296 px * 64 B) + ks taps 0..12 (3328 uint4) ----
    for (int p = tid; p < 1296; p += 512) {
        int r = p / 36, c = p - (p / 36) * 36;
        int gh = h0 + r - 2;
        int gw = w0 + c - 2;
        uint4 v0 = make_uint4(0u, 0u, 0u, 0u), v1 = v0, v2 = v0, v3 = v0;
        if ((unsigned)gh < 256u && (unsigned)gw < 256u) {
            const uint4* s = (const uint4*)(Xb + ((size_t)(gh * 256 + gw)) * 64);
            v0 = s[0]; v1 = s[1]; v2 = s[2]; v3 = s[3];
        }
        xt[0 * 1297 + p] = v0;
        xt[1 * 1297 + p] = v1;
        xt[2 * 1297 + p] = v2;
        xt[3 * 1297 + p] = v3;
    }
    #pragma unroll
    for (int k = 0; k < 7; ++k) {
        int lin = tid + k * 512;
        if (lin < 3328) ks_s[lin] = ksq[lin];
    }
    __syncthreads();

    int wave = tid >> 6, lane = tid & 63;
    int lO = lane & 15, ks4 = lane >> 4;
    int bidx = lO * 4 + ks4;

    f32x4 acc[8][4] = {};
    int baseA[8];
    #pragma unroll
    for (int m = 0; m < 8; ++m)
        baseA[m] = 1297 * ks4 + (wave * 4 + (m >> 1)) * 36 + (m & 1) * 16 + lO;

    f16x8 Af[2][8], Bf[2][4];

    // ---- phase 1: taps 0..12 from ks_s slots 0..12 ----
    #pragma unroll
    for (int m = 0; m < 8; ++m)
        Af[0][m] = __builtin_bit_cast(f16x8, xt[baseA[m]]);
    #pragma unroll
    for (int n = 0; n < 4; ++n)
        Bf[0][n] = __builtin_bit_cast(f16x8, ks_s[n * 64 + bidx]);

    #pragma unroll
    for (int t = 0; t < 13; ++t) {
        const int cur = t & 1, nxt = cur ^ 1;
        if (t < 12) {
            const int t1 = t + 1;
            const int aoff = (t1 / 5) * 36 + (t1 % 5);
            #pragma unroll
            for (int m = 0; m < 8; ++m)
                Af[nxt][m] = __builtin_bit_cast(f16x8, xt[baseA[m] + aoff]);
            #pragma unroll
            for (int n = 0; n < 4; ++n)
                Bf[nxt][n] = __builtin_bit_cast(f16x8, ks_s[t1 * 256 + n * 64 + bidx]);
        }
        #pragma unroll
        for (int m = 0; m < 8; ++m) {
            #pragma unroll
            for (int n = 0; n < 4; ++n)
                acc[m][n] = __builtin_amdgcn_mfma_f32_16x16x32_f16(Af[cur][m], Bf[cur][n], acc[m][n], 0, 0, 0);
        }
    }

    // ---- restage: ks taps 13..24 -> slots 0..11 ----
    __syncthreads();
    #pragma unroll
    for (int k = 0; k < 6; ++k) {
        int lin = tid + k * 512;
        if (lin < 3072) ks_s[lin] = ksq[3328 + lin];
    }
    __syncthreads();

    // ---- phase 2: taps 13..24 from ks_s slots 0..11 ----
    {
        const int aoff13 = (13 / 5) * 36 + (13 % 5);
        #pragma unroll
        for (int m = 0; m < 8; ++m)
            Af[1][m] = __builtin_bit_cast(f16x8, xt[baseA[m] + aoff13]);
        #pragma unroll
        for (int n = 0; n < 4; ++n)
            Bf[1][n] = __builtin_bit_cast(f16x8, ks_s[n * 64 + bidx]);
    }
    #pragma unroll
    for (int t = 13; t < 25; ++t) {
        const int cur = t & 1, nxt = cur ^ 1;
        if (t < 24) {
            const int t1 = t + 1;
            const int aoff = (t1 / 5) * 36 + (t1 % 5);
            #pragma unroll
            for (int m = 0; m < 8; ++m)
                Af[nxt][m] = __builtin_bit_cast(f16x8, xt[baseA[m] + aoff]);
            #pragma unroll
            for (int n = 0; n < 4; ++n)
                Bf[nxt][n] = __builtin_bit_cast(f16x8, ks_s[(t1 - 13) * 256 + n * 64 + bidx]);
        }
        #pragma unroll
        for (int m = 0; m < 8; ++m) {
            #pragma unroll
            for (int n = 0; n < 4; ++n)
                acc[m][n] = __builtin_amdgcn_mfma_f32_16x16x32_f16(Af[cur][m], Bf[cur][n], acc[m][n], 0, 0, 0);
        }
    }

    // ---- store: out[b][O&7][O>>3][h][w] * (2pi/8); full 128-B lines ----
    #pragma unroll
    for (int m = 0; m < 8; ++m) {
        int gh  = h0 + wave * 4 + (m >> 1);
        int gwb = w0 + (m & 1) * 16 + ks4 * 4;
        #pragma unroll
        for (int n = 0; n < 4; ++n) {
            int O = n * 16 + lO;
            float* op = out + (((size_t)(b * 8 + (O & 7)) * 8 + (O >> 3)) << 16)
                            + gh * 256 + gwb;
            *(f32x4*)op = acc[m][n] * PI4_F;
        }
    }
}

// ---- fallback (small ws): round-3 single-kernel conv reading f32 X ----
__global__ __launch_bounds__(512, 4) void conv_kernel_f32(const float* __restrict__ X,
                                                          const __half* __restrict__ ksh,
                                                          float* __restrict__ out) {
    __shared__ uint4 xt[720 * 5];
    int blk = blockIdx.x;
    int b = blk >> 7;
    int rem = blk & 127;
    int h0 = (rem >> 3) << 4;
    int w0 = (rem & 7) << 5;
    int tid = threadIdx.x;
    const float* Xb = X + (size_t)b * 32 * 65536;
    for (int lin = tid; lin < 2880; lin += 512) {
        int slotq = lin / 720;
        int pxi = lin - slotq * 720;
        int r = pxi / 36;
        int c = pxi - r * 36;
        int gh = h0 + r - 2;
        int gw = w0 + c - 2;
        union { __half h[8]; uint4 u; } pk;
        if ((unsigned)gh < 256u && (unsigned)gw < 256u) {
            const float* src = Xb + (size_t)slotq * 8 * 65536 + gh * 256 + gw;
            #pragma unroll
            for (int j = 0; j < 8; ++j) pk.h[j] = __float2half(src[j * 65536]);
        } else {
            pk.u = make_uint4(0u, 0u, 0u, 0u);
        }
        xt[pxi * 5 + slotq] = pk.u;
    }
    __syncthreads();
    int wave = tid >> 6, lane = tid & 63;
    int lO = lane & 15, ks4 = lane >> 4;
    const uint4* ksq = (const uint4*)ksh;
    int bidx = lO * 4 + ks4;
    f32x4 acc[4][4] = {};
    int baseA[4];
    #pragma unroll
    for (int q = 0; q < 4; ++q)
        baseA[q] = ((wave * 2 + (q >> 1)) * 36 + (q & 1) * 16 + lO) * 5 + ks4;
    f16x8 Bf[2][4];
    #pragma unroll
    for (int n = 0; n < 4; ++n)
        Bf[0][n] = __builtin_bit_cast(f16x8, ksq[n * 64 + bidx]);
    #pragma unroll
    for (int t = 0; t < 25; ++t) {
        const int cur = t & 1, nxt = cur ^ 1;
        f16x8 Af[4];
        #pragma unroll
        for (int q = 0; q < 4; ++q)
            Af[q] = __builtin_bit_cast(f16x8, xt[baseA[q] + ((t / 5) * 36 + (t % 5)) * 5]);
        if (t < 24) {
            #pragma unroll
            for (int n = 0; n < 4; ++n)
                Bf[nxt][n] = __builtin_bit_cast(f16x8, ksq[(t + 1) * 256 + n * 64 + bidx]);
        }
        #pragma unroll
        for (int q = 0; q < 4; ++q)
            #pragma unroll
            for (int n = 0; n < 4; ++n)
                acc[q][n] = __builtin_amdgcn_mfma_f32_16x16x32_f16(Af[q], Bf[cur][n], acc[q][n], 0, 0, 0);
    }
    #pragma unroll
    for (int q = 0; q < 4; ++q) {
        int gh = h0 + wave * 2 + (q >> 1);
        int gwb = w0 + (q & 1) * 16 + ks4 * 4;
        #pragma unroll
        for (int n = 0; n < 4; ++n) {
            int O = n * 16 + lO;
            float* op = out + (((size_t)(b * 8 + (O & 7)) * 8 + (O >> 3)) << 16) + gh * 256 + gwb;
            *(f32x4*)op = acc[q][n] * PI4_F;
        }
    }
}

extern "C" void kernel_launch(void* const* d_in, const int* in_sizes, int n_in,
                              void* d_out, int out_size, void* d_ws, size_t ws_size,
                              hipStream_t stream) {
    const float* X = (const float*)d_in[0];       // (8, 4, 8, 256, 256) f32
    const float* w = (const float*)d_in[1];       // (4, 200, 8) f32
    float* outp = (float*)d_out;                  // (8, 8, 8, 256, 256) f32
    char* ws = (char*)d_ws;
    __half* ksh = (__half*)ws;                    // 102.4 KB

    build_ks_kernel<<<200, 256, 0, stream>>>(w, ksh);

    if (ws_size >= XH_OFF + XH_BYTES) {
        __half* Xh = (__half*)(ws + XH_OFF);      // 33.55 MB fp16 HWC
        hwc_kernel<<<8 * 256, 256, 0, stream>>>(X, Xh);
        conv_hwc_kernel<<<8 * 64, 512, 0, stream>>>(Xh, ksh, outp);
    } else {
        conv_kernel_f32<<<8 * 16 * 8, 512, 0, stream>>>(X, ksh, outp);
    }
}

// Round 13
// 98.357 us; speedup vs baseline: 1.1235x; 1.1235x over previous
//
#include <hip/hip_runtime.h>
#include <hip/hip_fp16.h>
#include <math.h>

#define PI_F      3.14159265358979323846f
#define TWO_PI_F  6.28318530717958647692f
#define PI4_F     0.78539816339744830962f   // pi/4 == ROT_SCALE == 2pi/8

typedef _Float16 f16x8 __attribute__((ext_vector_type(8)));
typedef float    f32x4 __attribute__((ext_vector_type(4)));

__device__ __forceinline__ float sgn(float t) {
    return (t > 0.f) ? 1.f : ((t < 0.f) ? -1.f : 0.f);
}

__device__ __forceinline__ float b2(float x) {
    float a = x - 0.5f;
    float b = x - 1.5f;
    float c = 1.f + 2.f * x;
    float d = 3.f + 2.f * x;
    return (-3.f * a * a * sgn(0.5f - x)
            + b * b * sgn(1.5f - x)
            - 0.75f * c * c * sgn(0.5f + x)
            + 0.25f * d * d * sgn(1.5f + x)) * 0.25f;
}

// ks_h[t][O][I] fp16.  t = dx*5+dy, O = r0*8+o, I = i*8+r
__global__ void build_ks_kernel(const float* __restrict__ w, __half* __restrict__ ksh) {
    int g = blockIdx.x * 256 + threadIdx.x;
    if (g >= 64 * 32 * 25) return;
    int O = g & 63;
    int rest = g >> 6;
    int t = rest % 25;
    int I = rest / 25;
    int r0 = O >> 3, o = O & 7;
    int i = I >> 3, r = I & 7;
    int x = t / 5, y = t % 5;

    float theta = -(float)r0 * PI4_F;
    float cth = cosf(theta), sth = sinf(theta);
    float fx = (float)(x - 2), fy = (float)(y - 2);
    float xc = fx * cth - fy * sth;
    float yc = fx * sth + fy * cth;

    float rotv[8];
    float rs = (float)r * PI4_F + theta;
    #pragma unroll
    for (int mr = 0; mr < 8; ++mr) {
        float v = (float)mr * PI4_F - rs + PI_F;
        float md = fmodf(v, TWO_PI_F);
        if (md < 0.f) md += TWO_PI_F;
        rotv[mr] = b2((md - PI_F) / PI4_F);
    }

    float sum = 0.f;
    for (int mx = 0; mx < 25; ++mx) {
        float cx = (float)(mx / 5 - 2);
        float cy = (float)(mx % 5 - 2);
        float bx = b2(cx - xc) * b2(cy - yc);
        if (bx != 0.f) {
            const float* wp = w + (size_t)(i * 200 + mx * 8) * 8 + o;
            #pragma unroll
            for (int mr = 0; mr < 8; ++mr)
                sum = fmaf(bx * rotv[mr], wp[mr * 8], sum);
        }
    }
    ksh[(size_t)(t * 64 + O) * 32 + I] = __float2half(sum);
}

// Implicit-GEMM conv with FUSED f32->fp16 HWC staging (no pre-pass, no Xh).
// 32h x 32w px tile per 512-thread block (8 waves), all 64 O.
// LDS xt[slot(4 k-planes)][1296 px (36x36 halo)] uint4, stride 1297 (83 KB).
// Stage: slot-plane-minor sweep; each task reads 8 f32 (plane-strided,
// coalesced across lanes), converts, writes one ds_write_b128.
// Tap loop = round-8 structure verbatim: wave owns 4 h-rows = 8 M-tiles x
// 4 N-tiles (32 MFMA/tap), fresh A ds_reads, 1-deep B-from-L2 prefetch,
// setprio around the MFMA burst. Stores: full 128-B lines per plane-row.
__global__ __launch_bounds__(512, 2) void conv_fused_kernel(const float* __restrict__ X,
                                                            const __half* __restrict__ ksh,
                                                            float* __restrict__ out) {
    __shared__ uint4 xt[4 * 1297];   // 82.9 KB

    int bid = blockIdx.x;
    int b   = bid >> 6;              // 8 batches, b-major
    int rem = bid & 63;              // 0..63
    int h0  = (rem >> 3) << 5;       // 8 h-strips of 32
    int w0  = (rem & 7) << 5;        // 8 w-strips of 32
    int tid = threadIdx.x;

    const float* Xb = X + (size_t)b * 32 * 65536;

    // ---- fused stage: f32 CHW -> fp16 [k-plane][px] LDS ----
    for (int lin = tid; lin < 4 * 1296; lin += 512) {
        int slot = lin / 1296;            // 0..3  (8 channels each)
        int p    = lin - slot * 1296;     // 0..1295
        int r = p / 36, c = p - (p / 36) * 36;
        int gh = h0 + r - 2;
        int gw = w0 + c - 2;
        union { __half hh[8]; uint4 u; } pk;
        if ((unsigned)gh < 256u && (unsigned)gw < 256u) {
            const float* src = Xb + (size_t)slot * 8 * 65536 + gh * 256 + gw;
            #pragma unroll
            for (int j = 0; j < 8; ++j) pk.hh[j] = __float2half(src[j * 65536]);
        } else {
            pk.u = make_uint4(0u, 0u, 0u, 0u);
        }
        xt[slot * 1297 + p] = pk.u;
    }
    __syncthreads();

    int wave = tid >> 6, lane = tid & 63;
    int lO = lane & 15, ks4 = lane >> 4;
    int bidx = lO * 4 + ks4;
    const uint4* ksq = (const uint4*)ksh;

    f32x4 acc[8][4] = {};
    int baseA[8];
    #pragma unroll
    for (int m = 0; m < 8; ++m)
        baseA[m] = 1297 * ks4 + (wave * 4 + (m >> 1)) * 36 + (m & 1) * 16 + lO;

    // ---- 25-tap loop: fresh A reads, 1-deep B prefetch double-buffer ----
    f16x8 Bf[2][4];
    #pragma unroll
    for (int n = 0; n < 4; ++n)
        Bf[0][n] = __builtin_bit_cast(f16x8, ksq[n * 64 + bidx]);

    #pragma unroll
    for (int t = 0; t < 25; ++t) {
        const int cur = t & 1, nxt = cur ^ 1;
        const int aoff = (t / 5) * 36 + (t % 5);

        f16x8 Af[8];
        #pragma unroll
        for (int m = 0; m < 8; ++m)
            Af[m] = __builtin_bit_cast(f16x8, xt[baseA[m] + aoff]);

        if (t < 24) {
            const int t1 = t + 1;
            #pragma unroll
            for (int n = 0; n < 4; ++n)
                Bf[nxt][n] = __builtin_bit_cast(f16x8, ksq[t1 * 256 + n * 64 + bidx]);
        }

        __builtin_amdgcn_s_setprio(1);
        #pragma unroll
        for (int m = 0; m < 8; ++m) {
            #pragma unroll
            for (int n = 0; n < 4; ++n)
                acc[m][n] = __builtin_amdgcn_mfma_f32_16x16x32_f16(Af[m], Bf[cur][n], acc[m][n], 0, 0, 0);
        }
        __builtin_amdgcn_s_setprio(0);
    }

    // ---- store: out[b][O&7][O>>3][h][w] * (2pi/8); full 128-B lines ----
    #pragma unroll
    for (int m = 0; m < 8; ++m) {
        int gh  = h0 + wave * 4 + (m >> 1);
        int gwb = w0 + (m & 1) * 16 + ks4 * 4;
        #pragma unroll
        for (int n = 0; n < 4; ++n) {
            int O = n * 16 + lO;
            float* op = out + (((size_t)(b * 8 + (O & 7)) * 8 + (O >> 3)) << 16)
                            + gh * 256 + gwb;
            *(f32x4*)op = acc[m][n] * PI4_F;
        }
    }
}

extern "C" void kernel_launch(void* const* d_in, const int* in_sizes, int n_in,
                              void* d_out, int out_size, void* d_ws, size_t ws_size,
                              hipStream_t stream) {
    const float* X = (const float*)d_in[0];       // (8, 4, 8, 256, 256) f32
    const float* w = (const float*)d_in[1];       // (4, 200, 8) f32
    float* outp = (float*)d_out;                  // (8, 8, 8, 256, 256) f32
    __half* ksh = (__half*)d_ws;                  // 102.4 KB

    build_ks_kernel<<<200, 256, 0, stream>>>(w, ksh);
    conv_fused_kernel<<<8 * 64, 512, 0, stream>>>(X, ksh, outp);
}

// Round 14
// 94.080 us; speedup vs baseline: 1.1746x; 1.0455x over previous
//
#include <hip/hip_runtime.h>
#include <hip/hip_fp16.h>
#include <math.h>

#define PI_F      3.14159265358979323846f
#define TWO_PI_F  6.28318530717958647692f
#define PI4_F     0.78539816339744830962f   // pi/4 == ROT_SCALE == 2pi/8

typedef _Float16 f16x8 __attribute__((ext_vector_type(8)));
typedef float    f32x4 __attribute__((ext_vector_type(4)));

__device__ __forceinline__ float sgn(float t) {
    return (t > 0.f) ? 1.f : ((t < 0.f) ? -1.f : 0.f);
}

__device__ __forceinline__ float b2(float x) {
    float a = x - 0.5f;
    float b = x - 1.5f;
    float c = 1.f + 2.f * x;
    float d = 3.f + 2.f * x;
    return (-3.f * a * a * sgn(0.5f - x)
            + b * b * sgn(1.5f - x)
            - 0.75f * c * c * sgn(0.5f + x)
            + 0.25f * d * d * sgn(1.5f + x)) * 0.25f;
}

// ks_h[t][O][I] fp16.  t = dx*5+dy, O = r0*8+o, I = i*8+r
__global__ void build_ks_kernel(const float* __restrict__ w, __half* __restrict__ ksh) {
    int g = blockIdx.x * 256 + threadIdx.x;
    if (g >= 64 * 32 * 25) return;
    int O = g & 63;
    int rest = g >> 6;
    int t = rest % 25;
    int I = rest / 25;
    int r0 = O >> 3, o = O & 7;
    int i = I >> 3, r = I & 7;
    int x = t / 5, y = t % 5;

    float theta = -(float)r0 * PI4_F;
    float cth = cosf(theta), sth = sinf(theta);
    float fx = (float)(x - 2), fy = (float)(y - 2);
    float xc = fx * cth - fy * sth;
    float yc = fx * sth + fy * cth;

    float rotv[8];
    float rs = (float)r * PI4_F + theta;
    #pragma unroll
    for (int mr = 0; mr < 8; ++mr) {
        float v = (float)mr * PI4_F - rs + PI_F;
        float md = fmodf(v, TWO_PI_F);
        if (md < 0.f) md += TWO_PI_F;
        rotv[mr] = b2((md - PI_F) / PI4_F);
    }

    float sum = 0.f;
    for (int mx = 0; mx < 25; ++mx) {
        float cx = (float)(mx / 5 - 2);
        float cy = (float)(mx % 5 - 2);
        float bx = b2(cx - xc) * b2(cy - yc);
        if (bx != 0.f) {
            const float* wp = w + (size_t)(i * 200 + mx * 8) * 8 + o;
            #pragma unroll
            for (int mr = 0; mr < 8; ++mr)
                sum = fmaf(bx * rotv[mr], wp[mr * 8], sum);
        }
    }
    ksh[(size_t)(t * 64 + O) * 32 + I] = __float2half(sum);
}

// Implicit-GEMM conv, fused f32->fp16 staging, sized for 2 blocks/CU.
// Block = 256 threads (4 waves), tile 16h x 32w px, all 64 O.
// LDS xt[slot(4 k-planes)][720 px (20x36 halo)] uint4, stride 721 (46.1 KB)
//   -> 2 blocks co-resident (92 KB LDS, 232 regs = 2 waves/SIMD per block,
//      4 waves/SIMD total): block B's stage/store overlaps block A's MFMA.
// Per wave: 4 h-rows = 8 M-tiles x 4 N-tiles, 32 MFMA/tap (r8 structure).
__global__ __launch_bounds__(256, 2) void conv_fused_kernel(const float* __restrict__ X,
                                                            const __half* __restrict__ ksh,
                                                            float* __restrict__ out) {
    __shared__ uint4 xt[4 * 721];    // 46,144 B

    int bid = blockIdx.x;
    int b   = bid >> 7;              // 8 batches, b-major
    int rem = bid & 127;             // 0..127
    int h0  = (rem >> 3) << 4;       // 16 h-strips of 16
    int w0  = (rem & 7) << 5;        // 8 w-strips of 32
    int tid = threadIdx.x;

    const float* Xb = X + (size_t)b * 32 * 65536;

    // ---- fused stage: f32 CHW -> fp16 [k-plane][px] LDS ----
    for (int lin = tid; lin < 4 * 720; lin += 256) {
        int slot = lin / 720;             // 0..3  (8 channels each)
        int p    = lin - slot * 720;      // 0..719
        int r = p / 36, c = p - (p / 36) * 36;
        int gh = h0 + r - 2;
        int gw = w0 + c - 2;
        union { __half hh[8]; uint4 u; } pk;
        if ((unsigned)gh < 256u && (unsigned)gw < 256u) {
            const float* src = Xb + (size_t)slot * 8 * 65536 + gh * 256 + gw;
            #pragma unroll
            for (int j = 0; j < 8; ++j) pk.hh[j] = __float2half(src[j * 65536]);
        } else {
            pk.u = make_uint4(0u, 0u, 0u, 0u);
        }
        xt[slot * 721 + p] = pk.u;
    }
    __syncthreads();

    int wave = tid >> 6, lane = tid & 63;
    int lO = lane & 15, ks4 = lane >> 4;
    int bidx = lO * 4 + ks4;
    const uint4* ksq = (const uint4*)ksh;

    f32x4 acc[8][4] = {};
    int baseA[8];
    #pragma unroll
    for (int m = 0; m < 8; ++m)
        baseA[m] = 721 * ks4 + (wave * 4 + (m >> 1)) * 36 + (m & 1) * 16 + lO;

    // ---- 25-tap loop: fresh A reads, 1-deep B prefetch double-buffer ----
    f16x8 Bf[2][4];
    #pragma unroll
    for (int n = 0; n < 4; ++n)
        Bf[0][n] = __builtin_bit_cast(f16x8, ksq[n * 64 + bidx]);

    #pragma unroll
    for (int t = 0; t < 25; ++t) {
        const int cur = t & 1, nxt = cur ^ 1;
        const int aoff = (t / 5) * 36 + (t % 5);

        f16x8 Af[8];
        #pragma unroll
        for (int m = 0; m < 8; ++m)
            Af[m] = __builtin_bit_cast(f16x8, xt[baseA[m] + aoff]);

        if (t < 24) {
            const int t1 = t + 1;
            #pragma unroll
            for (int n = 0; n < 4; ++n)
                Bf[nxt][n] = __builtin_bit_cast(f16x8, ksq[t1 * 256 + n * 64 + bidx]);
        }

        __builtin_amdgcn_s_setprio(1);
        #pragma unroll
        for (int m = 0; m < 8; ++m) {
            #pragma unroll
            for (int n = 0; n < 4; ++n)
                acc[m][n] = __builtin_amdgcn_mfma_f32_16x16x32_f16(Af[m], Bf[cur][n], acc[m][n], 0, 0, 0);
        }
        __builtin_amdgcn_s_setprio(0);
    }

    // ---- store: out[b][O&7][O>>3][h][w] * (2pi/8) ----
    #pragma unroll
    for (int m = 0; m < 8; ++m) {
        int gh  = h0 + wave * 4 + (m >> 1);
        int gwb = w0 + (m & 1) * 16 + ks4 * 4;
        #pragma unroll
        for (int n = 0; n < 4; ++n) {
            int O = n * 16 + lO;
            float* op = out + (((size_t)(b * 8 + (O & 7)) * 8 + (O >> 3)) << 16)
                            + gh * 256 + gwb;
            *(f32x4*)op = acc[m][n] * PI4_F;
        }
    }
}

extern "C" void kernel_launch(void* const* d_in, const int* in_sizes, int n_in,
                              void* d_out, int out_size, void* d_ws, size_t ws_size,
                              hipStream_t stream) {
    const float* X = (const float*)d_in[0];       // (8, 4, 8, 256, 256) f32
    const float* w = (const float*)d_in[1];       // (4, 200, 8) f32
    float* outp = (float*)d_out;                  // (8, 8, 8, 256, 256) f32
    __half* ksh = (__half*)d_ws;                  // 102.4 KB

    build_ks_kernel<<<200, 256, 0, stream>>>(w, ksh);
    conv_fused_kernel<<<8 * 128, 256, 0, stream>>>(X, ksh, outp);
}